// Round 9
// baseline (1205.799 us; speedup 1.0000x reference)
//
#include <hip/hip_runtime.h>
#include <cstddef>

static constexpr int   NN      = 2048;
static constexpr int   TPB_B   = 256;   // build_cost block
static constexpr int   TPB     = 512;   // main kernel block (8 waves)
static constexpr int   NWB     = TPB / 64;          // 8 waves/block
static constexpr int   NB      = 256;               // main grid blocks (1/CU)
static constexpr int   MAX_IT  = 100;
static constexpr float EPS     = 0.1f;
static constexpr float INV_EPS = 10.0f;
// logf(1/2048 + 1e-8)
static constexpr float LOG_AB  = -7.6245985063594f;
static constexpr float THRESH  = 0.1f;

#define ALOAD(p)     __hip_atomic_load((p),  __ATOMIC_RELAXED, __HIP_MEMORY_SCOPE_AGENT)
#define ASTORE(p, x) __hip_atomic_store((p), (x), __ATOMIC_RELAXED, __HIP_MEMORY_SCOPE_AGENT)

typedef unsigned long long u64;

// ---------------------------------------------------------------------------
// Cost matrix build + state zeroing. C[i][j] = sum_d (x[i,d]-y[j,d])^2.
// ---------------------------------------------------------------------------
__global__ __launch_bounds__(TPB_B)
void build_cost(const float* __restrict__ x, const float* __restrict__ y,
                float* __restrict__ C, float* __restrict__ CT,
                unsigned* __restrict__ zz, int zcount,
                int c_aligned, int use_ct)
{
    __shared__ float xs[64][65];
    __shared__ float ys[64][65];
    const int t  = threadIdx.x;
    const int bi = blockIdx.y, bj = blockIdx.x;

    // row bi==0 (32 blocks) zeroes the signal region in parallel
    // (harness poisons ws with 0xAA before every call; 0xAA.. would falsely
    //  validate epoch checks -> must re-zero every launch)
    if (bi == 0) {
        int per = (zcount + 31) / 32;
        int lo = bj * per;
        int hi = lo + per; if (hi > zcount) hi = zcount;
        for (int idx = lo + t; idx < hi; idx += TPB_B) zz[idx] = 0u;
    }

#pragma unroll
    for (int k = 0; k < 16; ++k) {
        int idx = t + TPB_B * k;
        int r = idx >> 6, c = idx & 63;
        xs[r][c] = x[(size_t)(bi * 64 + r) * 64 + c];
        ys[r][c] = y[(size_t)(bj * 64 + r) * 64 + c];
    }
    __syncthreads();

    const int ti0 = (t >> 4) * 4;
    const int tj0 = (t & 15) * 4;
    float acc[4][4] = {};
#pragma unroll 8
    for (int d = 0; d < 64; ++d) {
        float xv[4], yv[4];
#pragma unroll
        for (int k = 0; k < 4; ++k) xv[k] = xs[ti0 + k][d];
#pragma unroll
        for (int l = 0; l < 4; ++l) yv[l] = ys[tj0 + l][d];
#pragma unroll
        for (int k = 0; k < 4; ++k)
#pragma unroll
            for (int l = 0; l < 4; ++l) {
                float df = xv[k] - yv[l];
                acc[k][l] = fmaf(df, df, acc[k][l]);
            }
    }

#pragma unroll
    for (int k = 0; k < 4; ++k) {
        size_t off = (size_t)(bi * 64 + ti0 + k) * NN + bj * 64 + tj0;
        if (c_aligned) {
            *(float4*)(C + off) = make_float4(acc[k][0], acc[k][1], acc[k][2], acc[k][3]);
        } else {
            C[off + 0] = acc[k][0]; C[off + 1] = acc[k][1];
            C[off + 2] = acc[k][2]; C[off + 3] = acc[k][3];
        }
    }
    if (use_ct) {
#pragma unroll
        for (int l = 0; l < 4; ++l) {
            size_t off = (size_t)(bj * 64 + tj0 + l) * NN + bi * 64 + ti0;
            *(float4*)(CT + off) = make_float4(acc[0][l], acc[1][l], acc[2][l], acc[3][l]);
        }
    }
}

// ---------------------------------------------------------------------------
// Helpers
// ---------------------------------------------------------------------------
__device__ __forceinline__ void load_row32(const float* row, int lane,
                                           int aligned, float c[32])
{
    if (aligned) {
        const float4* r4 = (const float4*)row;
#pragma unroll
        for (int k = 0; k < 8; ++k) {
            float4 A = r4[lane + 64 * k];
            c[4*k+0] = A.x; c[4*k+1] = A.y; c[4*k+2] = A.z; c[4*k+3] = A.w;
        }
    } else {
#pragma unroll
        for (int k = 0; k < 8; ++k) {
            const float* p = row + 4 * (lane + 64 * k);
            c[4*k+0] = p[0]; c[4*k+1] = p[1]; c[4*k+2] = p[2]; c[4*k+3] = p[3];
        }
    }
}

__device__ __forceinline__ void lds_row32(const float* sv, int lane, float b[32])
{
    const float4* s4 = (const float4*)sv;
#pragma unroll
    for (int k = 0; k < 8; ++k) {
        float4 A = s4[lane + 64 * k];
        b[4*k+0] = A.x; b[4*k+1] = A.y; b[4*k+2] = A.z; b[4*k+3] = A.w;
    }
}

// wave-level lse of (b-c)*INV_EPS over 2048 elems; result on ALL lanes.
__device__ __forceinline__ float wave_lse(const float c[32], const float b[32])
{
    float M = b[0] - c[0];
#pragma unroll
    for (int k = 1; k < 32; ++k) M = fmaxf(M, b[k] - c[k]);
#pragma unroll
    for (int off = 1; off < 64; off <<= 1) M = fmaxf(M, __shfl_xor(M, off));
    float Ms = M * INV_EPS;
    float s = 0.0f;
#pragma unroll
    for (int k = 0; k < 32; ++k) s += __expf(fmaf(b[k] - c[k], INV_EPS, -Ms));
#pragma unroll
    for (int off = 1; off < 64; off <<= 1) s += __shfl_xor(s, off);
    return Ms + __logf(s);
}

// ---------------------------------------------------------------------------
// Poll own replica until all 2048 self-validating {epoch|value} entries show
// epoch >= ep; deposit values into LDS dst and accumulate per-wave
// sum(|new-old|) into pdw[wave] (fixed order -> bit-identical in every block).
// Caller must __syncthreads() afterwards.
// ---------------------------------------------------------------------------
__device__ __forceinline__ void poll_deposit(const u64* rep, unsigned ep,
                                             float* dst, float* pdw, int t)
{
    const int lane = t & 63, w = t >> 6;
    const int base = 4 * t;
    u64 d0, d1, d2, d3;
    for (;;) {
        d0 = ALOAD(rep + base + 0); d1 = ALOAD(rep + base + 1);
        d2 = ALOAD(rep + base + 2); d3 = ALOAD(rep + base + 3);
        bool ok = ((unsigned)(d0 >> 32) >= ep) & ((unsigned)(d1 >> 32) >= ep)
                & ((unsigned)(d2 >> 32) >= ep) & ((unsigned)(d3 >> 32) >= ep);
        if (ok) break;
    }
    float n0 = __uint_as_float((unsigned)d0);
    float n1 = __uint_as_float((unsigned)d1);
    float n2 = __uint_as_float((unsigned)d2);
    float n3 = __uint_as_float((unsigned)d3);
    float4 o = ((float4*)dst)[t];
    float du = fabsf(n0 - o.x) + fabsf(n1 - o.y) + fabsf(n2 - o.z) + fabsf(n3 - o.w);
    ((float4*)dst)[t] = make_float4(n0, n1, n2, n3);
#pragma unroll
    for (int off = 1; off < 64; off <<= 1) du += __shfl_xor(du, off);
    if (lane == 0) pdw[w] = du;
}

// ---------------------------------------------------------------------------
// Main cooperative kernel. 256 blocks x 512 thr; wave w of block b owns
// row/col i = b*8+w. C row + CT col in registers (loop-invariant).
// Cross-block broadcast: G replicated mailboxes of self-validating u64
// {epoch|f32} (one 8B bypass store per value per replica — no fences, no
// drains, no flags). Each block polls only replica b%G -> ~NB/G pollers per
// cache line per round (R8 had all 2048 waves on 128 lines: bank-serialized).
// Convergence diff computed LOCALLY from LDS old/new (identical fixed-order
// reduction in every block -> bit-identical -> uniform break), zero RTTs.
// Cm may alias out+1 (crow/ccol register-resident before any overwrite).
// ---------------------------------------------------------------------------
__global__ __launch_bounds__(TPB)
void sinkhorn_main(const float* Cm, const float* __restrict__ CT,
                   u64* __restrict__ repA, u64* __restrict__ repB,
                   u64* __restrict__ costb,
                   float* out, int c_aligned, int use_ct,
                   int gmask, int gshift)
{
    __shared__ float su[2048];     // current u vector
    __shared__ float svv[2048];    // current v vector
    __shared__ float swave[NWB];   // own 8 values to post
    __shared__ float sdu[NWB];     // per-wave diff partials (row)
    __shared__ float sdv[NWB];     // per-wave diff partials (col)
    __shared__ float sred4[4];
    __shared__ float sdiff;
    const int t = threadIdx.x, lane = t & 63, w = t >> 6, b = blockIdx.x;
    const int i = b * NWB + w;
    const u64* myA = repA + ((size_t)(b & gmask)) * 2048;
    const u64* myB = repB + ((size_t)(b & gmask)) * 2048;

    // loop-invariant C row / CT col -> registers
    float crow[32], ccol[32];
    load_row32(Cm + (size_t)i * NN, lane, c_aligned, crow);
    if (use_ct) {
        load_row32(CT + (size_t)i * NN, lane, 1, ccol);
    } else {
#pragma unroll
        for (int k = 0; k < 8; ++k)
#pragma unroll
            for (int kk = 0; kk < 4; ++kk)
                ccol[4*k+kk] = Cm[(size_t)(4 * (lane + 64 * k) + kk) * NN + i];
    }

    for (int k = t; k < 2048; k += TPB) { su[k] = 0.0f; svv[k] = 0.0f; }
    __syncthreads();

    float u_keep = 0.0f;
    float b32[32];
    const int nposts = 8 << gshift;   // 8 values x G replicas

    for (int it = 0; it < MAX_IT; ++it) {
        const unsigned ep = (unsigned)(it + 1);

        // ---- A: deferred convergence check (diff of epoch `it`, all local)
        if (it >= 1) {
            if (t == 0) {
                float s = 0.0f;
#pragma unroll
                for (int k = 0; k < NWB; ++k) s += sdu[k];
#pragma unroll
                for (int k = 0; k < NWB; ++k) s += sdv[k];
                sdiff = s;
            }
            __syncthreads();
            if (sdiff < THRESH) break;   // state: su=u(it), svv=v(it), u_keep=u(it)
        }

        // ---- B: row compute u(ep) from svv = v(it)
        lds_row32(svv, lane, b32);
        float lse   = wave_lse(crow, b32);
        float u_new = EPS * (LOG_AB - lse);          // wave-uniform
        if (lane == 0) swave[w] = u_new;
        __syncthreads();

        // ---- C: post u to all replicas; poll own replica -> su, sdu
        if (t < nposts)
            ASTORE(&repA[((size_t)(t & gmask)) * 2048 + b * NWB + (t >> gshift)],
                   ((u64)ep << 32) | __float_as_uint(swave[t >> gshift]));
        poll_deposit(myA, ep, su, sdu, t);
        u_keep = u_new;
        __syncthreads();

        // ---- D: col compute v(ep) from su = u(ep)
        lds_row32(su, lane, b32);
        lse = wave_lse(ccol, b32);
        float v_new = EPS * (LOG_AB - lse);
        if (lane == 0) swave[w] = v_new;
        __syncthreads();

        // ---- E: post v; poll -> svv, sdv
        if (t < nposts)
            ASTORE(&repB[((size_t)(t & gmask)) * 2048 + b * NWB + (t >> gshift)],
                   ((u64)ep << 32) | __float_as_uint(swave[t >> gshift]));
        poll_deposit(myB, ep, svv, sdv, t);
        __syncthreads();
    }

    // ---- epilogue: pi = exp((u_i + v_j - C_ij)/eps), cost = sum(pi*C)
    float cpart = 0.0f;
    {
        lds_row32(svv, lane, b32);         // final v
        const float ui = u_keep;           // own row's final u (wave-uniform)
        float* orow = out + 1 + (size_t)i * NN;
#pragma unroll
        for (int k = 0; k < 8; ++k) {
#pragma unroll
            for (int kk = 0; kk < 4; ++kk) {
                float cc = crow[4*k+kk];
                float p  = __expf((ui + b32[4*k+kk] - cc) * INV_EPS);
                cpart = fmaf(p, cc, cpart);
                orow[4 * (lane + 64 * k) + kk] = p;  // crow in regs: alias-safe
            }
        }
    }
#pragma unroll
    for (int off = 1; off < 64; off <<= 1) cpart += __shfl_xor(cpart, off);
    if (lane == 0) sdu[w] = cpart;
    __syncthreads();
    if (t == 0) {
        float pc = 0.0f;
#pragma unroll
        for (int k = 0; k < NWB; ++k) pc += sdu[k];
        ASTORE(&costb[b], (1ull << 32) | __float_as_uint(pc));
    }
    if (b == 0) {                          // block 0 gathers the cost total
        if (t < 256) {
            u64 h;
            for (;;) { h = ALOAD(&costb[t]); if ((unsigned)(h >> 32) >= 1u) break; }
            float pc = __uint_as_float((unsigned)h);
#pragma unroll
            for (int off = 1; off < 64; off <<= 1) pc += __shfl_xor(pc, off);
            if (lane == 0) sred4[w] = pc;
        }
        __syncthreads();
        if (t == 0) out[0] = sred4[0] + sred4[1] + sred4[2] + sred4[3];
    }
}

// ---------------------------------------------------------------------------
extern "C" void kernel_launch(void* const* d_in, const int* in_sizes, int n_in,
                              void* d_out, int out_size, void* d_ws, size_t ws_size,
                              hipStream_t stream)
{
    (void)in_sizes; (void)n_in; (void)out_size;
    const float* x = (const float*)d_in[0];
    const float* y = (const float*)d_in[1];
    float* out = (float*)d_out;
    char*  ws  = (char*)d_ws;

    const size_t CB = (size_t)NN * NN * sizeof(float);   // 16 MiB
    auto zbytes = [](int G) -> size_t { return ((size_t)G * 4096 + 256) * 8; };

    float *Cm, *CT; char* zz;
    int c_aligned, use_ct, G;
    if (ws_size >= 2 * CB + zbytes(32)) {          // C, CT, signals in ws
        Cm = (float*)ws; CT = (float*)(ws + CB); zz = ws + 2 * CB;
        c_aligned = 1; use_ct = 1; G = 32;
    } else if (ws_size >= CB + zbytes(32)) {       // C in out+1, CT in ws
        Cm = out + 1; CT = (float*)ws; zz = ws + CB;
        c_aligned = 0; use_ct = 1; G = 32;
    } else if (ws_size >= CB + zbytes(4)) {        // smaller replica set
        Cm = out + 1; CT = (float*)ws; zz = ws + CB;
        c_aligned = 0; use_ct = 1; G = 4;
    } else if (ws_size >= zbytes(4)) {             // no CT (strided cols)
        Cm = out + 1; CT = nullptr; zz = ws;
        c_aligned = 0; use_ct = 0; G = 4;
    } else {                                       // minimal
        Cm = out + 1; CT = nullptr; zz = ws;
        c_aligned = 0; use_ct = 0; G = 1;
    }
    int gmask = G - 1;
    int gshift = (G == 32) ? 5 : (G == 4) ? 2 : 0;

    // u64 layout in zz: repA[0, G*2048) repB[G*2048, G*4096) costb[+256]
    u64* repA  = (u64*)zz;
    u64* repB  = repA + (size_t)G * 2048;
    u64* costb = repB + (size_t)G * 2048;
    int  zcount = (G * 4096 + 256) * 2;            // u32 elements to zero

    hipLaunchKernelGGL(build_cost, dim3(32, 32), dim3(TPB_B), 0, stream,
                       x, y, Cm, CT, (unsigned*)zz, zcount, c_aligned, use_ct);

    const float* Cmc = Cm;
    const float* CTc = CT;
    void* args[] = { (void*)&Cmc, (void*)&CTc, (void*)&repA, (void*)&repB,
                     (void*)&costb, (void*)&out, (void*)&c_aligned,
                     (void*)&use_ct, (void*)&gmask, (void*)&gshift };
    hipLaunchCooperativeKernel((void*)sinkhorn_main, dim3(NB), dim3(TPB),
                               args, 0, stream);
}